// Round 10
// baseline (554.591 us; speedup 1.0000x reference)
//
#include <hip/hip_runtime.h>
#include <hip/hip_bf16.h>

// GGCN: g1=relu(A@(x@W1)+b1); g2=relu(A@(g1@W2)+b2); out=relu(g2@Wd1+bd1)@Wd2+bd2
// N=16384, F=32, H=64, A dense f32 (1.07 GB, read 2x -> HBM floor ~341us).
// R10 = R6 (best, 453.8us) with K-step 64 -> 128: 512B per A-row DRAM visit
// (halves page activations/byte; granule series: 32B=840, 128B=519, 256B=454).
// To fit LDS: no sH tile -- B-frags load direct from L2-resident Ht (16B/lane,
// proven path in R3). A: lane owns 32B contiguous f32 (2 loads) -> pack8 ->
// b128 LDS write, swizzle (s<<3)|(ccA^row&7). Barrier-free wave-private dbuf,
// split-K=4 in block, epilogue identical to R6.

typedef __bf16 bf16x8 __attribute__((ext_vector_type(8)));
typedef float  f32x16 __attribute__((ext_vector_type(16)));
typedef float  f32x4v __attribute__((ext_vector_type(4)));
typedef int    i32x4  __attribute__((ext_vector_type(4)));

#define NNODE 16384
#define KDIM  16384
#define HCOL  64

__device__ inline i32x4 pack8(f32x4v a, f32x4v b){
  bf16x8 t;
  t[0]=(__bf16)a[0]; t[1]=(__bf16)a[1]; t[2]=(__bf16)a[2]; t[3]=(__bf16)a[3];
  t[4]=(__bf16)b[0]; t[5]=(__bf16)b[1]; t[6]=(__bf16)b[2]; t[7]=(__bf16)b[3];
  return __builtin_bit_cast(i32x4, t);
}
#define BC(x) __builtin_bit_cast(bf16x8, x)

// ---------------- big kernel: G = relu(A @ Ht^T + bias) ----------------
// block = 256 thr (4 waves). BM=64 rows. wave kw owns K-quarter (wave-private
// LDS dbuf, no main-loop barriers). Tile = 64 rows x 128k. 32 tiles.
__global__ __launch_bounds__(256, 1) void gcn_layer_kernel(
    const float* __restrict__ A,      // [16384][16384] f32
    const __bf16* __restrict__ Ht,    // [64][16384] bf16 (transposed H)
    const float* __restrict__ bias,   // [64]
    float* __restrict__ G)            // [16384][64] f32
{
  __shared__ i32x4 sA[4*2*1024];  // (kw,buf) x 64 rows x 16 chunks = 128 KB

  const int tid  = threadIdx.x;
  const int lane = tid & 63;
  const int kw   = tid >> 6;          // K-quarter 0..3
  const int row0 = blockIdx.x * 64;

  const int rA0  = lane >> 3;         // 0..7 staging row-in-group
  const int ccA  = lane & 7;          // lane's 32B sub-slot within a 256B half
  const int swz8 = ccA ^ rA0;         // 8-way XOR (row&7 == rA0)
  const int r    = lane & 31;
  const int hsub = lane >> 5;         // 8-k half of the 16-k MFMA window
  const int xs   = r & 7;

  const size_t k0 = (size_t)kw * 4096;

  f32x4v ra[32];                      // [gg][s][h] = gg*4 + s*2 + h

  // lane's f32 base: row0+rA0, k0 + ccA*8 (32B ownership: h=0/+4)
  const float* pA0 = A + (size_t)(row0 + rA0) * KDIM + k0 + (size_t)ccA*8;
  const __bf16* pB0 = Ht + (size_t)r * KDIM + k0 + (size_t)hsub*8;
  const __bf16* pB1 = pB0 + (size_t)32 * KDIM;

  auto stage_load = [&](int t){
    const float* pA = pA0 + (size_t)t*128;
    #pragma unroll
    for (int gg=0; gg<8; ++gg){                    // rows rA0 + gg*8
      const float* p = pA + (size_t)gg*8*KDIM;
      #pragma unroll
      for (int s=0; s<2; ++s){                     // two 256B halves of the 512B visit
        ra[gg*4+s*2+0] = __builtin_nontemporal_load((const f32x4v*)(p + s*64));
        ra[gg*4+s*2+1] = __builtin_nontemporal_load((const f32x4v*)(p + s*64 + 4));
      }
    }
  };

  auto stage_write = [&](int buf){
    i32x4* dA = &sA[(kw*2+buf)*1024];
    #pragma unroll
    for (int gg=0; gg<8; ++gg){
      #pragma unroll
      for (int s=0; s<2; ++s){
        int cp = (s<<3) | swz8;                    // phys 16B chunk (16 per row)
        dA[(rA0 + gg*8)*16 + cp] = pack8(ra[gg*4+s*2+0], ra[gg*4+s*2+1]);
      }
    }
  };

  f32x16 acc00 = {}, acc01 = {}, acc10 = {}, acc11 = {};

  auto compute = [&](int buf, int t){
    const i32x4* bA = &sA[(kw*2+buf)*1024];
    const __bf16* q0 = pB0 + (size_t)t*128;
    const __bf16* q1 = pB1 + (size_t)t*128;
    #pragma unroll
    for (int kk=0; kk<8; ++kk){
      int c  = kk*2 + hsub;
      int cp = (c & 8) | ((c & 7) ^ xs);
      bf16x8 a0 = BC(bA[r*16 + cp]);
      bf16x8 a1 = BC(bA[(r+32)*16 + cp]);
      bf16x8 b0 = BC(*(const i32x4*)(q0 + kk*16)); // Ht: L2-resident, direct
      bf16x8 b1 = BC(*(const i32x4*)(q1 + kk*16));
      acc00 = __builtin_amdgcn_mfma_f32_32x32x16_bf16(a0, b0, acc00, 0,0,0);
      acc01 = __builtin_amdgcn_mfma_f32_32x32x16_bf16(a0, b1, acc01, 0,0,0);
      acc10 = __builtin_amdgcn_mfma_f32_32x32x16_bf16(a1, b0, acc10, 0,0,0);
      acc11 = __builtin_amdgcn_mfma_f32_32x32x16_bf16(a1, b1, acc11, 0,0,0);
    }
  };

  // barrier-free per-wave pipeline over 32 tiles (k-quarter, 128 k each)
  stage_load(0);
  stage_write(0);
  stage_load(1);
  #pragma unroll 1
  for (int t=0; t<31; ++t){
    compute(t&1, t);
    stage_write((t+1)&1);
    if (t < 30) stage_load(t+2);
  }
  compute(1, 31);              // tile 31

  __syncthreads();             // red aliases kw0/kw1's sA regions

  // split-K=4 reduce: waves 1..3 dump partials, wave 0 combines (as R6)
  float* red = (float*)sA;     // 3 x 64x64 f32 = 48 KB
  if (kw > 0){
    float* rd = red + (size_t)(kw-1)*4096;
    #pragma unroll
    for (int j=0; j<16; ++j){
      int rr = (j&3) + 8*(j>>2) + 4*hsub;          // C/D layout [verified R1..R9]
      rd[(rr   )*64 + r]      = acc00[j];
      rd[(rr   )*64 + 32 + r] = acc01[j];
      rd[(rr+32)*64 + r]      = acc10[j];
      rd[(rr+32)*64 + 32 + r] = acc11[j];
    }
  }
  __syncthreads();
  if (kw == 0){
    #pragma unroll
    for (int j=0; j<16; ++j){
      int rr = (j&3) + 8*(j>>2) + 4*hsub;
      float v00 = acc00[j] + red[(rr   )*64+r]    + red[4096+(rr   )*64+r]    + red[8192+(rr   )*64+r]    + bias[r];
      float v01 = acc01[j] + red[(rr   )*64+32+r] + red[4096+(rr   )*64+32+r] + red[8192+(rr   )*64+32+r] + bias[32+r];
      float v10 = acc10[j] + red[(rr+32)*64+r]    + red[4096+(rr+32)*64+r]    + red[8192+(rr+32)*64+r]    + bias[r];
      float v11 = acc11[j] + red[(rr+32)*64+32+r] + red[4096+(rr+32)*64+32+r] + red[8192+(rr+32)*64+32+r] + bias[32+r];
      G[(size_t)(row0 + rr     )*HCOL + r]      = fmaxf(v00, 0.f);
      G[(size_t)(row0 + rr     )*HCOL + 32 + r] = fmaxf(v01, 0.f);
      G[(size_t)(row0 + rr + 32)*HCOL + r]      = fmaxf(v10, 0.f);
      G[(size_t)(row0 + rr + 32)*HCOL + 32 + r] = fmaxf(v11, 0.f);
    }
  }
}

// ---------------- projection: out[h][n] = sum_f in[n][f]*W[f][h], bf16 out ----------------
template<int F>
__global__ __launch_bounds__(128) void proj_T_kernel(
    const float* __restrict__ in,   // [N][F]
    const float* __restrict__ W,    // [F][64]
    __bf16* __restrict__ out)       // [64][N]
{
  constexpr int FP = F + 4;
  __shared__ float sWt[64*FP];
  __shared__ short sOut[64*136];

  int tid = threadIdx.x;
  for (int e = tid; e < 64*F; e += 128){
    int h = e / F, j = e - h*F;
    sWt[h*FP + j] = W[j*64 + h];
  }
  __syncthreads();

  const size_t n = (size_t)blockIdx.x*128 + tid;
  float rowv[F];
  #pragma unroll
  for (int j=0; j<F; j+=4){
    f32x4v v = *(const f32x4v*)(in + n*F + j);
    rowv[j]=v[0]; rowv[j+1]=v[1]; rowv[j+2]=v[2]; rowv[j+3]=v[3];
  }
  #pragma unroll
  for (int h=0; h<64; ++h){
    float s = 0.f;
    #pragma unroll
    for (int j=0; j<F; j+=4){
      f32x4v w = *(const f32x4v*)&sWt[h*FP + j];
      s += rowv[j]*w[0] + rowv[j+1]*w[1] + rowv[j+2]*w[2] + rowv[j+3]*w[3];
    }
    sOut[h*136 + tid] = __builtin_bit_cast(short, (__bf16)s);
  }
  __syncthreads();

  const size_t n0 = (size_t)blockIdx.x*128;
  #pragma unroll
  for (int pi=0; pi<8; ++pi){
    int p = pi*128 + tid;
    int h = p >> 4, cc = p & 15;
    i32x4 v = *(const i32x4*)&sOut[h*136 + cc*8];
    *(i32x4*)(out + (size_t)h*NNODE + n0 + cc*8) = v;
  }
}

// ---------------- tail MLP: out[n] = relu(g2[n]@Wd1+bd1)@Wd2 + bd2 ----------------
__global__ __launch_bounds__(256) void tail_kernel(
    const float* __restrict__ g2,
    const float* __restrict__ Wd1,
    const float* __restrict__ bd1,
    const float* __restrict__ Wd2,
    const float* __restrict__ bd2,
    float* __restrict__ outp)
{
  __shared__ float sW[64*32];
  __shared__ float sb1[32], sw2[32];
  int tid = threadIdx.x;
  for (int e=tid; e<2048; e+=256) sW[e] = Wd1[e];
  if (tid < 32){ sb1[tid] = bd1[tid]; sw2[tid] = Wd2[tid]; }
  __syncthreads();

  size_t n = (size_t)blockIdx.x*256 + tid;
  float rv[64];
  #pragma unroll
  for (int j=0;j<64;j+=4){
    f32x4v v = *(const f32x4v*)(g2 + n*64 + j);
    rv[j]=v[0]; rv[j+1]=v[1]; rv[j+2]=v[2]; rv[j+3]=v[3];
  }
  float o = 0.f;
  #pragma unroll
  for (int c=0;c<32;++c){
    float s = sb1[c];
    #pragma unroll
    for (int j=0;j<64;++j) s += rv[j]*sW[j*32 + c];
    o += fmaxf(s, 0.f) * sw2[c];
  }
  outp[n] = o + bd2[0];
}

extern "C" void kernel_launch(void* const* d_in, const int* in_sizes, int n_in,
                              void* d_out, int out_size, void* d_ws, size_t ws_size,
                              hipStream_t stream)
{
  const float* x   = (const float*)d_in[0];
  const float* a   = (const float*)d_in[1];
  const float* W1  = (const float*)d_in[2];
  const float* b1  = (const float*)d_in[3];
  const float* W2  = (const float*)d_in[4];
  const float* b2  = (const float*)d_in[5];
  const float* Wd1 = (const float*)d_in[6];
  const float* bd1 = (const float*)d_in[7];
  const float* Wd2 = (const float*)d_in[8];
  const float* bd2 = (const float*)d_in[9];
  float* outp = (float*)d_out;

  char* ws = (char*)d_ws;                       // needs 12 MB
  __bf16* Ht1 = (__bf16*)(ws);                  // [64][16384] bf16, 2 MB
  __bf16* Ht2 = (__bf16*)(ws + (2u<<20));       // 2 MB
  float*  g1  = (float*)(ws + (4u<<20));        // [16384][64] f32, 4 MB
  float*  g2  = (float*)(ws + (8u<<20));        // 4 MB

  proj_T_kernel<32><<<128, 128, 0, stream>>>(x,  W1, Ht1);
  gcn_layer_kernel <<<256, 256, 0, stream>>>(a, Ht1, b1, g1);
  proj_T_kernel<64><<<128, 128, 0, stream>>>(g1, W2, Ht2);
  gcn_layer_kernel <<<256, 256, 0, stream>>>(a, Ht2, b2, g2);
  tail_kernel      <<<64, 256, 0, stream>>>(g2, Wd1, bd1, Wd2, bd2, outp);
}